// Round 1
// baseline (206.729 us; speedup 1.0000x reference)
//
#include <hip/hip_runtime.h>

typedef unsigned short ushort_t;
typedef short bf16x8 __attribute__((ext_vector_type(8)));
typedef float fp32x4 __attribute__((ext_vector_type(4)));

#define BS 4096
#define NROW 8192
#define D 512
#define TILE 128
#define BK 32
#define INV_T 10.0f

__device__ __forceinline__ unsigned short f2bf(float f) {
  unsigned int u = __float_as_uint(f);
  u += 0x7fffu + ((u >> 16) & 1u);
  return (unsigned short)(u >> 16);
}

__device__ __forceinline__ void g2l16(const void* g, void* l) {
  __builtin_amdgcn_global_load_lds(
      (const __attribute__((address_space(1))) unsigned int*)g,
      (__attribute__((address_space(3))) unsigned int*)l, 16, 0, 0);
}

// One block per row: compute 1/||row||, write bf16-normalized row.
__global__ __launch_bounds__(256) void normalize_k(
    const float* __restrict__ zi, const float* __restrict__ zj,
    ushort_t* __restrict__ An) {
  const int r = blockIdx.x;
  const int t = threadIdx.x;
  const float* src = (r < BS) ? (zi + (size_t)r * D) : (zj + (size_t)(r - BS) * D);
  float2 v = ((const float2*)src)[t];
  float ss = v.x * v.x + v.y * v.y;
#pragma unroll
  for (int off = 1; off < 64; off <<= 1) ss += __shfl_xor(ss, off);
  __shared__ float ws[4];
  if ((t & 63) == 0) ws[t >> 6] = ss;
  __syncthreads();
  const float tot = ws[0] + ws[1] + ws[2] + ws[3];
  const float inv = 1.0f / fmaxf(sqrtf(tot), 1e-8f);
  ushort2 o;
  o.x = f2bf(v.x * inv);
  o.y = f2bf(v.y * inv);
  ((ushort2*)(An + (size_t)r * D))[t] = o;
}

// C = An * An^T (128x128 tile per block); epilogue: den[i] += sum_j!=i exp(sim/T),
// posAcc += sum over matched (i, (i+BS)%NROW) of sim/T.
__global__ __launch_bounds__(256) void gemm_expsum(
    const ushort_t* __restrict__ An, float* __restrict__ den,
    float* __restrict__ posAcc) {
  __shared__ __align__(16) ushort_t sA[TILE * BK];
  __shared__ __align__(16) ushort_t sB[TILE * BK];

  const int tid = threadIdx.x;
  const int lane = tid & 63;
  const int wave = tid >> 6;
  const int wr = wave >> 1;
  const int wc = wave & 1;
  const int rowBase = blockIdx.y * TILE;
  const int colBase = blockIdx.x * TILE;

  fp32x4 acc[4][4] = {};

  // staging: 512 16B chunks per tile; thread handles chunks tid and tid+256.
  // chunk c -> tile row c>>2, k-offset (c&3)*8 elems; LDS offset c*16 B
  // (contiguous in lane order as required by global_load_lds).
  const int c0 = tid;
  const int c1 = tid + 256;
  const ushort_t* gA0 = An + (size_t)(rowBase + (c0 >> 2)) * D + (c0 & 3) * 8;
  const ushort_t* gA1 = An + (size_t)(rowBase + (c1 >> 2)) * D + (c1 & 3) * 8;
  const ushort_t* gB0 = An + (size_t)(colBase + (c0 >> 2)) * D + (c0 & 3) * 8;
  const ushort_t* gB1 = An + (size_t)(colBase + (c1 >> 2)) * D + (c1 & 3) * 8;
  ushort_t* lA0 = sA + c0 * 8;
  ushort_t* lA1 = sA + c1 * 8;
  ushort_t* lB0 = sB + c0 * 8;
  ushort_t* lB1 = sB + c1 * 8;

  const int fr = lane & 15;        // A row / B col / C col within 16-tile
  const int kq = (lane >> 4) * 8;  // k quad offset

  for (int k0 = 0; k0 < D; k0 += BK) {
    g2l16(gA0 + k0, lA0);
    g2l16(gA1 + k0, lA1);
    g2l16(gB0 + k0, lB0);
    g2l16(gB1 + k0, lB1);
    __syncthreads();  // drains vmcnt -> LDS tiles complete
    bf16x8 a[4], b[4];
#pragma unroll
    for (int i = 0; i < 4; ++i) {
      a[i] = *(const bf16x8*)(sA + (wr * 64 + i * 16 + fr) * BK + kq);
      b[i] = *(const bf16x8*)(sB + (wc * 64 + i * 16 + fr) * BK + kq);
    }
#pragma unroll
    for (int i = 0; i < 4; ++i)
#pragma unroll
      for (int j = 0; j < 4; ++j)
        acc[i][j] =
            __builtin_amdgcn_mfma_f32_16x16x32_bf16(a[i], b[j], acc[i][j], 0, 0, 0);
    __syncthreads();  // guard LDS overwrite next iter
  }

  // Epilogue. C/D layout (16x16x32): col = lane&15, row = (lane>>4)*4 + reg.
  const int rq = (lane >> 4) * 4;
  float posPart = 0.0f;
#pragma unroll
  for (int i = 0; i < 4; ++i) {
    const int rbase = rowBase + wr * 64 + i * 16 + rq;
    float rs[4] = {0.0f, 0.0f, 0.0f, 0.0f};
#pragma unroll
    for (int j = 0; j < 4; ++j) {
      const int colg = colBase + wc * 64 + j * 16 + fr;
      fp32x4 v = acc[i][j];
#pragma unroll
      for (int rg = 0; rg < 4; ++rg) {
        const int rowg = rbase + rg;
        const float sv = v[rg] * INV_T;
        float e = __expf(sv);
        if (rowg == colg) e = 0.0f;  // exclude diagonal exactly
        rs[rg] += e;
        if (colg == ((rowg + BS) & (NROW - 1))) posPart += sv;
      }
    }
    // reduce over the 16 columns (lanes differing in bits 0..3)
#pragma unroll
    for (int rg = 0; rg < 4; ++rg) {
      float s = rs[rg];
      s += __shfl_xor(s, 1);
      s += __shfl_xor(s, 2);
      s += __shfl_xor(s, 4);
      s += __shfl_xor(s, 8);
      if (fr == 0) atomicAdd(&den[rbase + rg], s);
    }
  }
  posPart += __shfl_xor(posPart, 1);
  posPart += __shfl_xor(posPart, 2);
  posPart += __shfl_xor(posPart, 4);
  posPart += __shfl_xor(posPart, 8);
  posPart += __shfl_xor(posPart, 16);
  posPart += __shfl_xor(posPart, 32);
  if (lane == 0 && posPart != 0.0f) atomicAdd(posAcc, posPart);
}

__global__ __launch_bounds__(256) void finalize_k(
    const float* __restrict__ den, const float* __restrict__ posAcc,
    float* __restrict__ out) {
  const int t = threadIdx.x;
  float s = 0.0f;
  for (int i = t; i < NROW; i += 256) s += logf(den[i]);
#pragma unroll
  for (int off = 1; off < 64; off <<= 1) s += __shfl_xor(s, off);
  __shared__ float ws[4];
  if ((t & 63) == 0) ws[t >> 6] = s;
  __syncthreads();
  if (t == 0) {
    const float tot = ws[0] + ws[1] + ws[2] + ws[3];
    out[0] = (tot - posAcc[0]) * (1.0f / (float)NROW);
  }
}

extern "C" void kernel_launch(void* const* d_in, const int* in_sizes, int n_in,
                              void* d_out, int out_size, void* d_ws, size_t ws_size,
                              hipStream_t stream) {
  const float* zi = (const float*)d_in[0];
  const float* zj = (const float*)d_in[1];
  float* out = (float*)d_out;

  ushort_t* An = (ushort_t*)d_ws;                                // 8 MB bf16 normalized reps
  float* den = (float*)((char*)d_ws + (size_t)NROW * D * 2);     // 8192 fp32
  float* posAcc = den + NROW;                                    // 1 fp32

  hipMemsetAsync(den, 0, (NROW + 1) * sizeof(float), stream);
  normalize_k<<<NROW, 256, 0, stream>>>(zi, zj, An);
  dim3 grid(NROW / TILE, NROW / TILE);
  gemm_expsum<<<grid, 256, 0, stream>>>(An, den, posAcc);
  finalize_k<<<1, 256, 0, stream>>>(den, posAcc, out);
}

// Round 2
// 149.544 us; speedup vs baseline: 1.3824x; 1.3824x over previous
//
#include <hip/hip_runtime.h>

typedef unsigned short ushort_t;
typedef short bf16x8 __attribute__((ext_vector_type(8)));
typedef float fp32x4 __attribute__((ext_vector_type(4)));

#define BS 4096
#define NROW 8192
#define D 512
#define TILE 128
#define BK 32
#define NB (NROW / TILE)          // 64 block-rows/cols
#define NBLK (NB * (NB + 1) / 2)  // 2080 upper-triangle blocks
#define INV_T 10.0f

__device__ __forceinline__ unsigned short f2bf(float f) {
  unsigned int u = __float_as_uint(f);
  u += 0x7fffu + ((u >> 16) & 1u);
  return (unsigned short)(u >> 16);
}

__device__ __forceinline__ void g2l16(const void* g, void* l) {
  __builtin_amdgcn_global_load_lds(
      (const __attribute__((address_space(1))) unsigned int*)g,
      (__attribute__((address_space(3))) unsigned int*)l, 16, 0, 0);
}

// One block per row: compute 1/||row||, write bf16-normalized row.
__global__ __launch_bounds__(256) void normalize_k(
    const float* __restrict__ zi, const float* __restrict__ zj,
    ushort_t* __restrict__ An) {
  const int r = blockIdx.x;
  const int t = threadIdx.x;
  const float* src = (r < BS) ? (zi + (size_t)r * D) : (zj + (size_t)(r - BS) * D);
  float2 v = ((const float2*)src)[t];
  float ss = v.x * v.x + v.y * v.y;
#pragma unroll
  for (int off = 1; off < 64; off <<= 1) ss += __shfl_xor(ss, off);
  __shared__ float ws[4];
  if ((t & 63) == 0) ws[t >> 6] = ss;
  __syncthreads();
  const float tot = ws[0] + ws[1] + ws[2] + ws[3];
  const float inv = 1.0f / fmaxf(sqrtf(tot), 1e-8f);
  ushort2 o;
  o.x = f2bf(v.x * inv);
  o.y = f2bf(v.y * inv);
  ((ushort2*)(An + (size_t)r * D))[t] = o;
}

// Upper-triangle (bi<=bj) 128x128 tiles of sim = An*An^T.
// Off-diagonal tiles: den[row] += rowsum(exp), den[col] += colsum(exp) (symmetry).
// Diagonal tiles: den[row] += rowsum(exp) with row==col masked.
// posAcc += sim/T over entries col == row+BS (upper copy only; doubled in finalize).
__global__ __launch_bounds__(256) void gemm_expsum(
    const ushort_t* __restrict__ An, float* __restrict__ den,
    float* __restrict__ posAcc) {
  __shared__ __align__(16) ushort_t sA[TILE * BK];
  __shared__ __align__(16) ushort_t sB[TILE * BK];

  // decode linear block id -> (bi, bj), bi <= bj
  int rem = blockIdx.x;
  int bi = 0;
  while (rem >= NB - bi) { rem -= NB - bi; ++bi; }
  const int bj = bi + rem;
  const bool diag = (bi == bj);
  const int rowBase = bi * TILE;
  const int colBase = bj * TILE;

  const int tid = threadIdx.x;
  const int lane = tid & 63;
  const int wave = tid >> 6;
  const int wr = wave >> 1;
  const int wc = wave & 1;

  fp32x4 acc[4][4] = {};

  // staging: 512 16B chunks per tile; thread handles chunks tid and tid+256.
  // LDS slot c holds global chunk (row = c>>2, q = (c&3) ^ ((row>>1)&3)):
  // XOR-swizzle makes the ds_read_b128 pattern 2-way (free) instead of 8-way.
  const int c0 = tid;
  const int c1 = tid + 256;
  const int r0 = c0 >> 2, q0 = (c0 & 3) ^ ((r0 >> 1) & 3);
  const int r1 = c1 >> 2, q1 = (c1 & 3) ^ ((r1 >> 1) & 3);
  const ushort_t* gA0 = An + (size_t)(rowBase + r0) * D + q0 * 8;
  const ushort_t* gA1 = An + (size_t)(rowBase + r1) * D + q1 * 8;
  const ushort_t* gB0 = An + (size_t)(colBase + r0) * D + q0 * 8;
  const ushort_t* gB1 = An + (size_t)(colBase + r1) * D + q1 * 8;
  ushort_t* lA0 = sA + c0 * 8;
  ushort_t* lA1 = sA + c1 * 8;
  ushort_t* lB0 = sB + c0 * 8;
  ushort_t* lB1 = sB + c1 * 8;

  const int fr = lane & 15;   // A row / B col within 16-tile
  const int q = lane >> 4;    // k quad index (0..3), 8 elems each

  for (int k0 = 0; k0 < D; k0 += BK) {
    g2l16(gA0 + k0, lA0);
    g2l16(gA1 + k0, lA1);
    g2l16(gB0 + k0, lB0);
    g2l16(gB1 + k0, lB1);
    __syncthreads();  // drains vmcnt -> LDS tiles complete
    bf16x8 a[4], b[4];
#pragma unroll
    for (int i = 0; i < 4; ++i) {
      const int ra = wr * 64 + i * 16 + fr;
      const int rb = wc * 64 + i * 16 + fr;
      a[i] = *(const bf16x8*)(sA + ra * BK + ((q ^ ((ra >> 1) & 3)) * 8));
      b[i] = *(const bf16x8*)(sB + rb * BK + ((q ^ ((rb >> 1) & 3)) * 8));
    }
#pragma unroll
    for (int i = 0; i < 4; ++i)
#pragma unroll
      for (int j = 0; j < 4; ++j)
        acc[i][j] =
            __builtin_amdgcn_mfma_f32_16x16x32_bf16(a[i], b[j], acc[i][j], 0, 0, 0);
    __syncthreads();  // guard LDS overwrite next iter
  }

  // Epilogue. C/D layout (16x16x32): col = lane&15, row = (lane>>4)*4 + reg.
  const int rq = q * 4;
  float posPart = 0.0f;
  float colAcc[4] = {0.0f, 0.0f, 0.0f, 0.0f};
#pragma unroll
  for (int i = 0; i < 4; ++i) {
    const int rbase = rowBase + wr * 64 + i * 16 + rq;
    float rs[4] = {0.0f, 0.0f, 0.0f, 0.0f};
#pragma unroll
    for (int j = 0; j < 4; ++j) {
      const int colg = colBase + wc * 64 + j * 16 + fr;
      fp32x4 v = acc[i][j];
#pragma unroll
      for (int rg = 0; rg < 4; ++rg) {
        const int rowg = rbase + rg;
        const float sv = v[rg] * INV_T;
        float e = __expf(sv);
        if (diag && rowg == colg) e = 0.0f;  // exclude matrix diagonal exactly
        rs[rg] += e;
        colAcc[j] += e;
        if (colg == rowg + BS) posPart += sv;  // only upper copy; doubled later
      }
    }
    // row sums: reduce over the 16 columns (lanes differing in bits 0..3)
#pragma unroll
    for (int rg = 0; rg < 4; ++rg) {
      float s = rs[rg];
      s += __shfl_xor(s, 1);
      s += __shfl_xor(s, 2);
      s += __shfl_xor(s, 4);
      s += __shfl_xor(s, 8);
      if (fr == 0) atomicAdd(&den[rbase + rg], s);
    }
  }
  if (!diag) {
    // col sums (symmetric contribution): reduce over rows = regs (done) + lanes
    // differing in bits 4..5
#pragma unroll
    for (int j = 0; j < 4; ++j) {
      float c = colAcc[j];
      c += __shfl_xor(c, 16);
      c += __shfl_xor(c, 32);
      if (q == 0) atomicAdd(&den[colBase + wc * 64 + j * 16 + fr], c);
    }
  }
  posPart += __shfl_xor(posPart, 1);
  posPart += __shfl_xor(posPart, 2);
  posPart += __shfl_xor(posPart, 4);
  posPart += __shfl_xor(posPart, 8);
  posPart += __shfl_xor(posPart, 16);
  posPart += __shfl_xor(posPart, 32);
  if (lane == 0 && posPart != 0.0f) atomicAdd(posAcc, posPart);
}

__global__ __launch_bounds__(256) void finalize_k(
    const float* __restrict__ den, const float* __restrict__ posAcc,
    float* __restrict__ out) {
  const int t = threadIdx.x;
  float s = 0.0f;
  for (int i = t; i < NROW; i += 256) s += logf(den[i]);
#pragma unroll
  for (int off = 1; off < 64; off <<= 1) s += __shfl_xor(s, off);
  __shared__ float ws[4];
  if ((t & 63) == 0) ws[t >> 6] = s;
  __syncthreads();
  if (t == 0) {
    const float tot = ws[0] + ws[1] + ws[2] + ws[3];
    // each unordered positive pair was counted once -> double it
    out[0] = (tot - 2.0f * posAcc[0]) * (1.0f / (float)NROW);
  }
}

extern "C" void kernel_launch(void* const* d_in, const int* in_sizes, int n_in,
                              void* d_out, int out_size, void* d_ws, size_t ws_size,
                              hipStream_t stream) {
  const float* zi = (const float*)d_in[0];
  const float* zj = (const float*)d_in[1];
  float* out = (float*)d_out;

  ushort_t* An = (ushort_t*)d_ws;                                // 8 MB bf16 normalized reps
  float* den = (float*)((char*)d_ws + (size_t)NROW * D * 2);     // 8192 fp32
  float* posAcc = den + NROW;                                    // 1 fp32

  hipMemsetAsync(den, 0, (NROW + 1) * sizeof(float), stream);
  normalize_k<<<NROW, 256, 0, stream>>>(zi, zj, An);
  gemm_expsum<<<NBLK, 256, 0, stream>>>(An, den, posAcc);
  finalize_k<<<1, 256, 0, stream>>>(den, posAcc, out);
}